// Round 13
// baseline (417.110 us; speedup 1.0000x reference)
//
#include <hip/hip_runtime.h>

typedef unsigned short u16;
typedef __attribute__((ext_vector_type(8))) short bf16x8;
typedef __attribute__((ext_vector_type(4))) float f32x4;
typedef __attribute__((ext_vector_type(2))) unsigned int u32x2;
typedef __attribute__((ext_vector_type(4))) unsigned int u32x4;

#define GAS __attribute__((address_space(1)))
#define LAS __attribute__((address_space(3)))
#define MFMA __builtin_amdgcn_mfma_f32_16x16x32_bf16
#define BAR() __builtin_amdgcn_s_barrier()
#define WAITV(n) asm volatile("s_waitcnt vmcnt(" #n ")" ::: "memory")

__device__ __forceinline__ void gload16(const void* g, void* l) {
  __builtin_amdgcn_global_load_lds((GAS void*)g, (LAS void*)l, 16, 0, 0);
}
__device__ __forceinline__ u16 f2b(float x) {
  union { float f; unsigned u; } c; c.f = x;
  unsigned r = c.u + 0x7fffu + ((c.u >> 16) & 1u);
  return (u16)(r >> 16);
}
__device__ __forceinline__ float b2f(u16 h) {
  union { unsigned u; float f; } c; c.u = ((unsigned)h) << 16;
  return c.f;
}
__device__ __forceinline__ unsigned cvtpk(float lo, float hi) {
  unsigned r;
  asm("v_cvt_pk_bf16_f32 %0, %1, %2" : "=v"(r) : "v"(lo), "v"(hi));
  return r;
}

// ---------------- fused fp32 -> bf16 conversion (all 5 tensors, 1 launch) -------
__global__ __launch_bounds__(256) void cvt_all(
    const float* __restrict__ hs, const float* __restrict__ wq,
    const float* __restrict__ wk, const float* __restrict__ wv,
    const float* __restrict__ wo, u16* __restrict__ hsb,
    u16* __restrict__ wqkv, u16* __restrict__ wob) {
  int i = blockIdx.x * 256 + threadIdx.x;
  const float* src;
  u16* dst;
  int off;
  if (i < 1048576) {
    src = hs; dst = hsb; off = i;
  } else if (i < 2097152) {
    src = wq; dst = wqkv; off = i - 1048576;
  } else if (i < 2359296) {
    src = wk; dst = wqkv + 8388608; off = i - 2097152;
  } else if (i < 2621440) {
    src = wv; dst = wqkv + 10485760; off = i - 2359296;
  } else {
    src = wo; dst = wob; off = i - 2621440;
  }
  const float4* s4 = (const float4*)src;
  float4 a = s4[(size_t)off * 2], b = s4[(size_t)off * 2 + 1];
  u32x4 v;
  v[0] = (unsigned)f2b(a.x) | ((unsigned)f2b(a.y) << 16);
  v[1] = (unsigned)f2b(a.z) | ((unsigned)f2b(a.w) << 16);
  v[2] = (unsigned)f2b(b.x) | ((unsigned)f2b(b.y) << 16);
  v[3] = (unsigned)f2b(b.z) | ((unsigned)f2b(b.w) << 16);
  *(u32x4*)(dst + (size_t)off * 8) = v;
}

// ============ 256x128 8-phase GEMM (T2+T3+T4+T5, perfect grid fill) ============
// C[m,n] = sum_k A[m,k]*B[n,k]. 8 waves as 2M x 4N; wave (wr=w>>2, wc=w&3) owns
// rows wr*128 + mi*16 (mi 0..7) x cols wc*32 + ni*16 (ni 0..1)  [128 x 32].
// BK=64. LDS 96KB: A dbuf 2x32KB (256 rows, 4 chunks of 64), B dbuf 2x16KB.
// Granule swizzle phys_kg = kg ^ (row&7) (involution, both sides).
// A chunk c = rows [c*64, c*64+64): phases 0-1 read chunks {0,2} (rows
// wr*128+0..63), phases 2-3 read {1,3} (rows wr*128+64..127). B read at tile
// head. Issue: q0:B0,B1 | q1:A0,A2 +WAITV(4) | q2:A1,A3 | q3:WAITV(2).
// Entry invariant: only {A1,A3} of current tile outstanding (same wait
// positions as the proven 256^2 schedule).
// MODE 0: scatter Q[B,32,S,128]/K[B,8,S,128]/V normal [B,8,S,128] (bf16)
// MODE 1: fp32 linear Dout[m * (tilesN*128) + n]
template <int MODE>
__global__ __launch_bounds__(512, 2) void gemmv2(
    const u16* __restrict__ A, const u16* __restrict__ B,
    u16* __restrict__ Dq, u16* __restrict__ Dk, u16* __restrict__ Dv,
    float* __restrict__ Dout, int K, int tilesN, int nwg) {
  __shared__ __attribute__((aligned(16))) u16 ldsA[2][256 * 64];
  __shared__ __attribute__((aligned(16))) u16 ldsB[2][128 * 64];
  const int tid = threadIdx.x;
  const int lane = tid & 63;
  const int w = tid >> 6;
  const int wr = w >> 2, wc = w & 3;  // 2M x 4N
  const int r = lane & 15, g = lane >> 4;

  int wg = blockIdx.x;
  const int cpx = nwg >> 3;
  wg = (wg & 7) * cpx + (wg >> 3);
  const int bx = wg % tilesN, by = wg / tilesN;
  const size_t m0 = (size_t)by * 256, n0 = (size_t)bx * 128;
  const int NT = K >> 6;

  auto stageA = [&](int dbuf, int c, int k0) {
    int slot = c * 512 + tid;      // c in 0..3 -> rows c*64 .. c*64+63
    int row = slot >> 3;
    int kg = (slot & 7) ^ (row & 7);
    gload16(A + (m0 + row) * (size_t)K + k0 + kg * 8,
            (char*)&ldsA[dbuf][0] + c * 8192 + w * 1024);
  };
  auto stageB = [&](int dbuf, int c, int k0) {
    int slot = c * 512 + tid;      // c in 0..1 -> rows 0..127
    int row = slot >> 3;
    int kg = (slot & 7) ^ (row & 7);
    gload16(B + (n0 + row) * (size_t)K + k0 + kg * 8,
            (char*)&ldsB[dbuf][0] + c * 8192 + w * 1024);
  };
  auto ldA = [&](int cur, int mi, int kk) -> bf16x8 {
    int row = wr * 128 + mi * 16 + r;  // max 255
    return *(const bf16x8*)((const char*)&ldsA[cur][0] + row * 128 +
                            (((kk << 2) + g) ^ (row & 7)) * 16);
  };
  auto ldB = [&](int cur, int ni, int kk) -> bf16x8 {
    int row = wc * 32 + ni * 16 + r;   // max 127
    return *(const bf16x8*)((const char*)&ldsB[cur][0] + row * 128 +
                            (((kk << 2) + g) ^ (row & 7)) * 16);
  };

  f32x4 acc[8][2];
#pragma unroll
  for (int i = 0; i < 8; ++i)
#pragma unroll
    for (int j = 0; j < 2; ++j) acc[i][j] = (f32x4){0.f, 0.f, 0.f, 0.f};

  // prologue: B0,B1,A0,A2 (needed by phases 0-1) then A1,A3; keep {A1,A3} open
  stageB(0, 0, 0); stageB(0, 1, 0);
  stageA(0, 0, 0); stageA(0, 2, 0);
  stageA(0, 1, 0); stageA(0, 3, 0);
  WAITV(2);
  BAR();

  bf16x8 bf_[2][2];

#define GPHASE(MI0, IS0, IS1, WAITCODE)                                    \
  {                                                                        \
    bf16x8 aA0 = ldA(cur, MI0, 0), aA1 = ldA(cur, MI0, 1);                 \
    bf16x8 aB0 = ldA(cur, MI0 + 1, 0), aB1 = ldA(cur, MI0 + 1, 1);         \
    IS0; IS1;                                                              \
    BAR();                                                                 \
    __builtin_amdgcn_s_setprio(1);                                         \
    _Pragma("unroll") for (int ni = 0; ni < 2; ++ni) {                     \
      acc[MI0][ni] = MFMA(aA0, bf_[ni][0], acc[MI0][ni], 0, 0, 0);         \
      acc[MI0][ni] = MFMA(aA1, bf_[ni][1], acc[MI0][ni], 0, 0, 0);         \
      acc[MI0 + 1][ni] = MFMA(aB0, bf_[ni][0], acc[MI0 + 1][ni], 0, 0, 0); \
      acc[MI0 + 1][ni] = MFMA(aB1, bf_[ni][1], acc[MI0 + 1][ni], 0, 0, 0); \
    }                                                                      \
    __builtin_amdgcn_s_setprio(0);                                         \
    WAITCODE;                                                              \
    BAR();                                                                 \
  }

  for (int t = 0; t < NT - 1; ++t) {
    const int cur = t & 1, nb = cur ^ 1;
    const int k1 = (t + 1) << 6;
#pragma unroll
    for (int ni = 0; ni < 2; ++ni) {
      bf_[ni][0] = ldB(cur, ni, 0);
      bf_[ni][1] = ldB(cur, ni, 1);
    }
    GPHASE(0, stageB(nb, 0, k1), stageB(nb, 1, k1), );
    GPHASE(2, stageA(nb, 0, k1), stageA(nb, 2, k1), WAITV(4));
    GPHASE(4, stageA(nb, 1, k1), stageA(nb, 3, k1), );
    GPHASE(6, , , WAITV(2));
  }
  {
    const int cur = (NT - 1) & 1;
#pragma unroll
    for (int ni = 0; ni < 2; ++ni) {
      bf_[ni][0] = ldB(cur, ni, 0);
      bf_[ni][1] = ldB(cur, ni, 1);
    }
    GPHASE(0, , , );
    GPHASE(2, , , WAITV(0));
    GPHASE(4, , , );
    GPHASE(6, , , );
  }
#undef GPHASE

  // epilogue: m = m0 + wr*128 + mi*16 + g*4 + j, n = n0 + wc*32 + ni*16 + r
#pragma unroll
  for (int mi = 0; mi < 8; ++mi)
#pragma unroll
    for (int ni = 0; ni < 2; ++ni)
#pragma unroll
      for (int j = 0; j < 4; ++j) {
        int m = (int)m0 + wr * 128 + mi * 16 + g * 4 + j;
        int n = (int)n0 + wc * 32 + ni * 16 + r;
        if (MODE == 0) {
          u16 hv = f2b(acc[mi][ni][j]);
          int b = m >> 11, s = m & 2047;
          if (n < 4096) {
            Dq[(((size_t)b * 32 + (n >> 7)) * 2048 + s) * 128 + (n & 127)] = hv;
          } else if (n < 5120) {
            int nn = n - 4096;
            Dk[(((size_t)b * 8 + (nn >> 7)) * 2048 + s) * 128 + (nn & 127)] = hv;
          } else {
            int nn = n - 5120;
            Dv[(((size_t)b * 8 + (nn >> 7)) * 2048 + s) * 128 + (nn & 127)] = hv;
          }
        } else {
          Dout[(size_t)m * (size_t)(tilesN * 128) + n] = acc[mi][ni][j];
        }
      }
}

// ---------------- V transpose: [16][2048][128] -> [16][128][2048] ----------------
__global__ __launch_bounds__(256) void transpose_v(const u16* __restrict__ V,
                                                   u16* __restrict__ VT) {
  __shared__ __attribute__((aligned(16))) u16 tile[64 * 72];
  const int tid = threadIdx.x;
  const int s0 = blockIdx.x * 64, d0 = blockIdx.y * 64, hz = blockIdx.z;
#pragma unroll
  for (int pp = 0; pp < 2; ++pp) {
    int row = pp * 32 + (tid >> 3), colg = tid & 7;
    u32x4 vv = *(const u32x4*)(V + ((size_t)hz * 2048 + s0 + row) * 128 + d0 + colg * 8);
    *(u32x4*)(&tile[row * 72 + colg * 8]) = vv;
  }
  __syncthreads();
#pragma unroll
  for (int pp = 0; pp < 2; ++pp) {
    int dr = pp * 32 + (tid >> 3), sg = tid & 7;
    u32x4 ov;
#pragma unroll
    for (int e2 = 0; e2 < 4; ++e2)
      ov[e2] = (unsigned)tile[(sg * 8 + 2 * e2) * 72 + dr] |
               ((unsigned)tile[(sg * 8 + 2 * e2 + 1) * 72 + dr] << 16);
    *(u32x4*)(VT + ((size_t)hz * 128 + d0 + dr) * 2048 + s0 + sg * 8) = ov;
  }
}

// ---------------- fused per-head RMSNorm + RoPE (Q and K in one launch) ---------
__global__ __launch_bounds__(256) void rms_rope_all(
    u16* __restrict__ Qb, u16* __restrict__ Kb,
    const float* __restrict__ cosT, const float* __restrict__ sinT,
    const float* __restrict__ qnw, const float* __restrict__ knw) {
  int idx = blockIdx.x * 256 + threadIdx.x;
  int row = idx >> 6;
  int lane = idx & 63;
  u16* rp;
  const float* nw;
  float oscale;
  if (row < 131072) {
    rp = Qb + (size_t)row * 128;
    nw = qnw;
    oscale = 0.08838834764831845f * 1.4426950408889634f;
  } else {
    rp = Kb + (size_t)(row - 131072) * 128;
    nw = knw;
    oscale = 1.0f;
  }
  int s = row & 2047;
  float x0 = b2f(rp[lane]);
  float x1 = b2f(rp[lane + 64]);
  float ss = x0 * x0 + x1 * x1;
#pragma unroll
  for (int m = 32; m >= 1; m >>= 1) ss += __shfl_xor(ss, m);
  float inv = rsqrtf(ss * (1.0f / 128.0f) + 1e-6f);
  x0 *= inv * nw[lane];
  x1 *= inv * nw[lane + 64];
  float c0 = cosT[s * 128 + lane], s0 = sinT[s * 128 + lane];
  float c1 = cosT[s * 128 + lane + 64], s1 = sinT[s * 128 + lane + 64];
  rp[lane] = f2b((x0 * c0 - x1 * s0) * oscale);
  rp[lane + 64] = f2b((x1 * c1 + x0 * s1) * oscale);
}

// ---------------- causal GQA flash attention (2 q-frags/wave + K/V dbuf) --------
__global__ __launch_bounds__(256, 2) void attn_fwd(const u16* __restrict__ Q,
                                                   const u16* __restrict__ Kg,
                                                   const u16* __restrict__ Vg,
                                                   u16* __restrict__ AO) {
  __shared__ __attribute__((aligned(16))) u16 Ks[2][64 * 128];
  __shared__ __attribute__((aligned(16))) u16 Vt[2][128 * 64];
  __shared__ __attribute__((aligned(16))) u16 Plds[4][32 * 64];
  const int tid = threadIdx.x;
  const int lane = tid & 63;
  const int w = tid >> 6;
  const int r = lane & 15, g = lane >> 4;
  const int p = blockIdx.x, h = blockIdx.y, b = blockIdx.z;
  const int hkv = h >> 2;

  const u16* Kp = Kg + (((size_t)b * 8 + hkv) * 2048) * 128;
  const u16* Vp = Vg + (((size_t)b * 8 + hkv) * 128) * 2048;

  const short one_bf = (short)0x3F80;
  const bf16x8 vones = {one_bf, one_bf, one_bf, one_bf, one_bf, one_bf, one_bf, one_bf};

#pragma unroll 1
  for (int phase = 0; phase < 2; ++phase) {
    const int qt = phase == 0 ? (15 - p) : p;
    const u16* Qp = Q + (((size_t)b * 32 + h) * 2048 + qt * 128 + w * 32) * 128;

    bf16x8 qf[2][4];
#pragma unroll
    for (int f = 0; f < 2; ++f)
#pragma unroll
      for (int kk = 0; kk < 4; ++kk)
        qf[f][kk] = *(const bf16x8*)(Qp + (f * 16 + r) * 128 + kk * 32 + g * 8);

    f32x4 off[2][8];
#pragma unroll
    for (int f = 0; f < 2; ++f)
#pragma unroll
      for (int i = 0; i < 8; ++i) off[f][i] = (f32x4){0.f, 0.f, 0.f, 0.f};
    f32x4 lr4[2] = {(f32x4){0.f, 0.f, 0.f, 0.f}, (f32x4){0.f, 0.f, 0.f, 0.f}};
    float mrun[2] = {-1e30f, -1e30f};
    const int qg0 = qt * 128 + w * 32 + r;
    const int qg1 = qg0 + 16;

    const u16* kst[4];
    const u16* vst[4];
#pragma unroll
    for (int c = 0; c < 4; ++c) {
      int t = c * 256 + tid;
      kst[c] = Kp + (size_t)(t >> 4) * 128 + (size_t)(((t & 15) ^ ((t >> 4) & 7)) * 8);
      int d = t >> 3;
      vst[c] = Vp + (size_t)d * 2048 + (size_t)(((t & 7) ^ ((d >> 1) & 7)) * 8);
    }
    auto stageKV = [&](int buf) {
#pragma unroll
      for (int c = 0; c < 4; ++c) {
        gload16(kst[c], (char*)&Ks[buf][0] + c * 4096 + w * 1024);
        kst[c] += 64 * 128;
      }
#pragma unroll
      for (int c = 0; c < 4; ++c) {
        gload16(vst[c], (char*)&Vt[buf][0] + c * 4096 + w * 1024);
        vst[c] += 64;
      }
    };

    const int nu = 2 * qt + 2;

    stageKV(0);
    WAITV(0);
    BAR();

    for (int kt = 0; kt < nu; ++kt) {
      const int cur = kt & 1;
      if (kt + 1 < nu) stageKV(cur ^ 1);

      const char* KsC = (const char*)&Ks[cur][0];
      const char* VtC = (const char*)&Vt[cur][0];

      f32x4 sc0[4], sc1[4];
#pragma unroll
      for (int ni = 0; ni < 4; ++ni) {
        f32x4 a0 = (f32x4){0.f, 0.f, 0.f, 0.f};
        f32x4 a1 = (f32x4){0.f, 0.f, 0.f, 0.f};
        int ro = ni * 16 + r;
#pragma unroll
        for (int kk = 0; kk < 4; ++kk) {
          int slot = (ro * 16 + kk * 4 + g) ^ (ro & 7);
          bf16x8 kf = *(const bf16x8*)(KsC + slot * 16);
          a0 = MFMA(kf, qf[0][kk], a0, 0, 0, 0);
          a1 = MFMA(kf, qf[1][kk], a1, 0, 0, 0);
        }
        sc0[ni] = a0;
        sc1[ni] = a1;
      }

      float pm0 = -3e30f, pm1 = -3e30f;
      if (kt >= 2 * qt) {
#pragma unroll
        for (int ni = 0; ni < 4; ++ni)
#pragma unroll
          for (int j = 0; j < 4; ++j) {
            int kvg = kt * 64 + ni * 16 + g * 4 + j;
            float s0 = sc0[ni][j], s1 = sc1[ni][j];
            s0 = (kvg > qg0) ? -1e30f : s0;
            s1 = (kvg > qg1) ? -1e30f : s1;
            sc0[ni][j] = s0; sc1[ni][j] = s1;
            pm0 = fmaxf(pm0, s0); pm1 = fmaxf(pm1, s1);
          }
      } else {
#pragma unroll
        for (int ni = 0; ni < 4; ++ni)
#pragma unroll
          for (int j = 0; j < 4; ++j) {
            pm0 = fmaxf(pm0, sc0[ni][j]);
            pm1 = fmaxf(pm1, sc1[ni][j]);
          }
      }
      pm0 = fmaxf(pm0, __shfl_xor(pm0, 16));
      pm0 = fmaxf(pm0, __shfl_xor(pm0, 32));
      pm1 = fmaxf(pm1, __shfl_xor(pm1, 16));
      pm1 = fmaxf(pm1, __shfl_xor(pm1, 32));

      if (__any(pm0 > mrun[0] + 11.0f)) {
        float mn = fmaxf(mrun[0], pm0);
        float sclq = exp2f(mrun[0] - mn);
        mrun[0] = mn;
        f32x4 sv4;
        sv4[0] = __shfl(sclq, g * 4 + 0);
        sv4[1] = __shfl(sclq, g * 4 + 1);
        sv4[2] = __shfl(sclq, g * 4 + 2);
        sv4[3] = __shfl(sclq, g * 4 + 3);
#pragma unroll
        for (int i = 0; i < 8; ++i) off[0][i] *= sv4;
        lr4[0] *= sv4;
      }
      if (__any(pm1 > mrun[1] + 11.0f)) {
        float mn = fmaxf(mrun[1], pm1);
        float sclq = exp2f(mrun[1] - mn);
        mrun[1] = mn;
        f32x4 sv4;
        sv4[0] = __shfl(sclq, g * 4 + 0);
        sv4[1] = __shfl(sclq, g * 4 + 1);
        sv4[2] = __shfl(sclq, g * 4 + 2);
        sv4[3] = __shfl(sclq, g * 4 + 3);
#pragma unroll
        for (int i = 0; i < 8; ++i) off[1][i] *= sv4;
        lr4[1] *= sv4;
      }

      {
        char* pw = (char*)&Plds[w][0];
        int sw = (r & 7) << 4;
#pragma unroll
        for (int ni = 0; ni < 4; ++ni) {
          u32x2 pr0, pr1;
          pr0[0] = cvtpk(exp2f(sc0[ni][0] - mrun[0]), exp2f(sc0[ni][1] - mrun[0]));
          pr0[1] = cvtpk(exp2f(sc0[ni][2] - mrun[0]), exp2f(sc0[ni][3] - mrun[0]));
          pr1[0] = cvtpk(exp2f(sc1[ni][0] - mrun[1]), exp2f(sc1[ni][1] - mrun[1]));
          pr1[1] = cvtpk(exp2f(sc1[ni][2] - mrun[1]), exp2f(sc1[ni][3] - mrun[1]));
          *(u32x2*)(pw + ((r * 128 + ni * 32 + g * 8) ^ sw)) = pr0;
          *(u32x2*)(pw + (((16 + r) * 128 + ni * 32 + g * 8) ^ sw)) = pr1;
        }
      }
      bf16x8 pa[2][2];
      {
        const char* pw = (const char*)&Plds[w][0];
        int sw = (r & 7) << 4;
#pragma unroll
        for (int kk = 0; kk < 2; ++kk) {
          pa[0][kk] = *(const bf16x8*)(pw + ((r * 128 + kk * 64 + g * 16) ^ sw));
          pa[1][kk] = *(const bf16x8*)(pw + (((16 + r) * 128 + kk * 64 + g * 16) ^ sw));
        }
      }

      lr4[0] = MFMA(pa[0][0], vones, lr4[0], 0, 0, 0);
      lr4[0] = MFMA(pa[0][1], vones, lr4[0], 0, 0, 0);
      lr4[1] = MFMA(pa[1][0], vones, lr4[1], 0, 0, 0);
      lr4[1] = MFMA(pa[1][1], vones, lr4[1], 0, 0, 0);

#pragma unroll
      for (int dd = 0; dd < 8; ++dd) {
        int d = dd * 16 + r;
#pragma unroll
        for (int kk = 0; kk < 2; ++kk) {
          int ph = (kk * 4 + g) ^ ((r >> 1) & 7);
          bf16x8 vf = *(const bf16x8*)(VtC + (size_t)d * 128 + ph * 16);
          off[0][dd] = MFMA(pa[0][kk], vf, off[0][dd], 0, 0, 0);
          off[1][dd] = MFMA(pa[1][kk], vf, off[1][dd], 0, 0, 0);
        }
      }

      WAITV(0);
      BAR();
    }

#pragma unroll
    for (int f = 0; f < 2; ++f) {
      f32x4 il4;
#pragma unroll
      for (int j = 0; j < 4; ++j) il4[j] = 1.0f / lr4[f][j];
      const size_t ob = (size_t)b * 2048 + qt * 128 + w * 32 + f * 16 + g * 4;
#pragma unroll
      for (int dd = 0; dd < 8; ++dd) {
        AO[(ob + 0) * 4096 + h * 128 + dd * 16 + r] = f2b(off[f][dd][0] * il4[0]);
        AO[(ob + 1) * 4096 + h * 128 + dd * 16 + r] = f2b(off[f][dd][1] * il4[1]);
        AO[(ob + 2) * 4096 + h * 128 + dd * 16 + r] = f2b(off[f][dd][2] * il4[2]);
        AO[(ob + 3) * 4096 + h * 128 + dd * 16 + r] = f2b(off[f][dd][3] * il4[3]);
      }
    }
  }
}

// ---------------- launch ----------------
extern "C" void kernel_launch(void* const* d_in, const int* in_sizes, int n_in,
                              void* d_out, int out_size, void* d_ws, size_t ws_size,
                              hipStream_t stream) {
  (void)in_sizes; (void)n_in; (void)out_size; (void)ws_size;
  const float* hs = (const float*)d_in[0];
  const float* cosT = (const float*)d_in[1];
  const float* sinT = (const float*)d_in[2];
  const float* wq = (const float*)d_in[3];
  const float* wk = (const float*)d_in[4];
  const float* wv = (const float*)d_in[5];
  const float* wo = (const float*)d_in[6];
  const float* qnw = (const float*)d_in[7];
  const float* knw = (const float*)d_in[8];
  float* out = (float*)d_out;

  char* ws = (char*)d_ws;
  u16* hsb  = (u16*)(ws);                   // [4096,2048]      16 MB
  u16* wqkv = (u16*)(ws + 16777216);        // [6144,2048]      24 MB
  u16* wob  = (u16*)(ws + 41943040);        // [2048,4096]      16 MB
  u16* Qb   = (u16*)(ws + 58720256);        // [2,32,2048,128]  32 MB
  u16* Kb   = (u16*)(ws + 92274688);        // [2,8,2048,128]    8 MB
  u16* VTb  = (u16*)(ws + 100663296);       // [2,8,128,2048]    8 MB (transposed)
  u16* AO   = (u16*)(ws + 109051904);       // [4096,4096]      32 MB
  u16* Vnrm = AO;                           // dead before attn

  // 1) fp32 -> bf16 (all tensors, one launch)
  cvt_all<<<14336, 256, 0, stream>>>(hs, wq, wk, wv, wo, hsb, wqkv, wob);

  // 2) fused QKV projection (256x128 8-phase, 768 blocks = 3 perfect rounds)
  gemmv2<0><<<768, 512, 0, stream>>>(hsb, wqkv, Qb, Kb, Vnrm, nullptr, 2048, 48, 768);

  // 2b) V -> V^T [b,hkv,d,s]
  transpose_v<<<dim3(32, 2, 16), 256, 0, stream>>>(Vnrm, VTb);

  // 3) per-head RMSNorm + RoPE for Q and K (one launch)
  rms_rope_all<<<40960, 256, 0, stream>>>(Qb, Kb, cosT, sinT, qnw, knw);

  // 4) causal GQA flash attention (QBLK=128, paired {15-p,p}) -> AO bf16
  attn_fwd<<<dim3(8, 32, 2), 256, 0, stream>>>(Qb, Kb, VTb, AO);

  // 5) output projection (256x128 8-phase, 256 blocks = 1 perfect round)
  gemmv2<1><<<256, 512, 0, stream>>>(AO, wob, nullptr, nullptr, nullptr, out,
                                     4096, 16, 256);
}

// Round 14
// 356.400 us; speedup vs baseline: 1.1703x; 1.1703x over previous
//
#include <hip/hip_runtime.h>

typedef unsigned short u16;
typedef __attribute__((ext_vector_type(8))) short bf16x8;
typedef __attribute__((ext_vector_type(4))) float f32x4;
typedef __attribute__((ext_vector_type(2))) unsigned int u32x2;
typedef __attribute__((ext_vector_type(4))) unsigned int u32x4;

#define GAS __attribute__((address_space(1)))
#define LAS __attribute__((address_space(3)))
#define MFMA __builtin_amdgcn_mfma_f32_16x16x32_bf16
#define BAR() __builtin_amdgcn_s_barrier()
#define WAITV(n) asm volatile("s_waitcnt vmcnt(" #n ")" ::: "memory")

__device__ __forceinline__ void gload16(const void* g, void* l) {
  __builtin_amdgcn_global_load_lds((GAS void*)g, (LAS void*)l, 16, 0, 0);
}
__device__ __forceinline__ u16 f2b(float x) {
  union { float f; unsigned u; } c; c.f = x;
  unsigned r = c.u + 0x7fffu + ((c.u >> 16) & 1u);
  return (u16)(r >> 16);
}
__device__ __forceinline__ float b2f(u16 h) {
  union { unsigned u; float f; } c; c.u = ((unsigned)h) << 16;
  return c.f;
}
__device__ __forceinline__ unsigned cvtpk(float lo, float hi) {
  unsigned r;
  asm("v_cvt_pk_bf16_f32 %0, %1, %2" : "=v"(r) : "v"(lo), "v"(hi));
  return r;
}

// ---------------- fused fp32 -> bf16 conversion (all 5 tensors, 1 launch) -------
__global__ __launch_bounds__(256) void cvt_all(
    const float* __restrict__ hs, const float* __restrict__ wq,
    const float* __restrict__ wk, const float* __restrict__ wv,
    const float* __restrict__ wo, u16* __restrict__ hsb,
    u16* __restrict__ wqkv, u16* __restrict__ wob) {
  int i = blockIdx.x * 256 + threadIdx.x;
  const float* src;
  u16* dst;
  int off;
  if (i < 1048576) {
    src = hs; dst = hsb; off = i;
  } else if (i < 2097152) {
    src = wq; dst = wqkv; off = i - 1048576;
  } else if (i < 2359296) {
    src = wk; dst = wqkv + 8388608; off = i - 2097152;
  } else if (i < 2621440) {
    src = wv; dst = wqkv + 10485760; off = i - 2359296;
  } else {
    src = wo; dst = wob; off = i - 2621440;
  }
  const float4* s4 = (const float4*)src;
  float4 a = s4[(size_t)off * 2], b = s4[(size_t)off * 2 + 1];
  u32x4 v;
  v[0] = (unsigned)f2b(a.x) | ((unsigned)f2b(a.y) << 16);
  v[1] = (unsigned)f2b(a.z) | ((unsigned)f2b(a.w) << 16);
  v[2] = (unsigned)f2b(b.x) | ((unsigned)f2b(b.y) << 16);
  v[3] = (unsigned)f2b(b.z) | ((unsigned)f2b(b.w) << 16);
  *(u32x4*)(dst + (size_t)off * 8) = v;
}

// ============ 256x256 8-phase GEMM (T2+T3+T4+T5) — proven template ============
template <int MODE>
__global__ __launch_bounds__(512, 2) void gemm256(
    const u16* __restrict__ A, const u16* __restrict__ B,
    u16* __restrict__ Dq, u16* __restrict__ Dk, u16* __restrict__ Dv,
    float* __restrict__ Dout, int K, int tilesN, int nwg) {
  __shared__ __attribute__((aligned(16))) u16 lds[2][2][2][128 * 64];
  const int tid = threadIdx.x;
  const int lane = tid & 63;
  const int w = tid >> 6;
  const int wr = w >> 2, wc = w & 3;
  const int r = lane & 15, g = lane >> 4;

  int wg = blockIdx.x;
  const int cpx = nwg >> 3;
  wg = (wg & 7) * cpx + (wg >> 3);
  const int bx = wg % tilesN, by = wg / tilesN;
  const size_t m0 = (size_t)by * 256, n0 = (size_t)bx * 256;
  const int NT = K >> 6;

  auto stage = [&](int dbuf, int op, int half, int c, int k0) {
    int slot = c * 512 + tid;
    int row = slot >> 3;
    int kg = (slot & 7) ^ (row & 7);
    const u16* src = (op == 0)
        ? A + (m0 + half * 128 + row) * (size_t)K + k0 + kg * 8
        : B + (n0 + half * 128 + row) * (size_t)K + k0 + kg * 8;
    gload16(src, (char*)&lds[dbuf][op][half][0] + c * 8192 + w * 1024);
  };
  auto ldA = [&](int cur, int mi, int kk) -> bf16x8 {
    int rowl = mi * 16 + r;
    return *(const bf16x8*)((const char*)&lds[cur][0][wr][0] + rowl * 128 +
                            (((kk << 2) + g) ^ (rowl & 7)) * 16);
  };
  auto ldB = [&](int cur, int ni, int kk) -> bf16x8 {
    int rowl = (wc & 1) * 64 + ni * 16 + r;
    return *(const bf16x8*)((const char*)&lds[cur][1][wc >> 1][0] + rowl * 128 +
                            (((kk << 2) + g) ^ (rowl & 7)) * 16);
  };

  f32x4 acc[8][4];
#pragma unroll
  for (int i = 0; i < 8; ++i)
#pragma unroll
    for (int j = 0; j < 4; ++j) acc[i][j] = (f32x4){0.f, 0.f, 0.f, 0.f};

  stage(0, 1, 0, 0, 0); stage(0, 1, 0, 1, 0);
  stage(0, 1, 1, 0, 0); stage(0, 1, 1, 1, 0);
  stage(0, 0, 0, 0, 0); stage(0, 0, 1, 0, 0);
  stage(0, 0, 0, 1, 0); stage(0, 0, 1, 1, 0);
  WAITV(2);
  BAR();

  bf16x8 bf_[4][2];

#define GPHASE(MI0, IS0, IS1, WAITCODE)                                    \
  {                                                                        \
    bf16x8 aA0 = ldA(cur, MI0, 0), aA1 = ldA(cur, MI0, 1);                 \
    bf16x8 aB0 = ldA(cur, MI0 + 1, 0), aB1 = ldA(cur, MI0 + 1, 1);         \
    IS0; IS1;                                                              \
    BAR();                                                                 \
    __builtin_amdgcn_s_setprio(1);                                         \
    _Pragma("unroll") for (int ni = 0; ni < 4; ++ni) {                     \
      acc[MI0][ni] = MFMA(aA0, bf_[ni][0], acc[MI0][ni], 0, 0, 0);         \
      acc[MI0][ni] = MFMA(aA1, bf_[ni][1], acc[MI0][ni], 0, 0, 0);         \
      acc[MI0 + 1][ni] = MFMA(aB0, bf_[ni][0], acc[MI0 + 1][ni], 0, 0, 0); \
      acc[MI0 + 1][ni] = MFMA(aB1, bf_[ni][1], acc[MI0 + 1][ni], 0, 0, 0); \
    }                                                                      \
    __builtin_amdgcn_s_setprio(0);                                         \
    WAITCODE;                                                              \
    BAR();                                                                 \
  }

  for (int t = 0; t < NT - 1; ++t) {
    const int cur = t & 1, nb = cur ^ 1;
    const int k1 = (t + 1) << 6;
#pragma unroll
    for (int ni = 0; ni < 4; ++ni) {
      bf_[ni][0] = ldB(cur, ni, 0);
      bf_[ni][1] = ldB(cur, ni, 1);
    }
    GPHASE(0, stage(nb, 1, 0, 0, k1), stage(nb, 1, 0, 1, k1), );
    GPHASE(2, stage(nb, 1, 1, 0, k1), stage(nb, 1, 1, 1, k1), WAITV(4));
    GPHASE(4, stage(nb, 0, 0, 0, k1), stage(nb, 0, 1, 0, k1), );
    GPHASE(6, stage(nb, 0, 0, 1, k1), stage(nb, 0, 1, 1, k1), WAITV(2));
  }
  {
    const int cur = (NT - 1) & 1;
#pragma unroll
    for (int ni = 0; ni < 4; ++ni) {
      bf_[ni][0] = ldB(cur, ni, 0);
      bf_[ni][1] = ldB(cur, ni, 1);
    }
    GPHASE(0, , , );
    GPHASE(2, , , WAITV(0));
    GPHASE(4, , , );
    GPHASE(6, , , );
  }
#undef GPHASE

#pragma unroll
  for (int mi = 0; mi < 8; ++mi)
#pragma unroll
    for (int ni = 0; ni < 4; ++ni)
#pragma unroll
      for (int j = 0; j < 4; ++j) {
        int m = (int)m0 + wr * 128 + mi * 16 + g * 4 + j;
        int n = (int)n0 + wc * 64 + ni * 16 + r;
        if (MODE == 0) {
          u16 hv = f2b(acc[mi][ni][j]);
          int b = m >> 11, s = m & 2047;
          if (n < 4096) {
            Dq[(((size_t)b * 32 + (n >> 7)) * 2048 + s) * 128 + (n & 127)] = hv;
          } else if (n < 5120) {
            int nn = n - 4096;
            Dk[(((size_t)b * 8 + (nn >> 7)) * 2048 + s) * 128 + (nn & 127)] = hv;
          } else {
            int nn = n - 5120;
            Dv[(((size_t)b * 8 + (nn >> 7)) * 2048 + s) * 128 + (nn & 127)] = hv;
          }
        } else {
          Dout[(size_t)m * (size_t)(tilesN * 256) + n] = acc[mi][ni][j];
        }
      }
}

// ---------------- V transpose: [16][2048][128] -> [16][128][2048] ----------------
__global__ __launch_bounds__(256) void transpose_v(const u16* __restrict__ V,
                                                   u16* __restrict__ VT) {
  __shared__ __attribute__((aligned(16))) u16 tile[64 * 72];
  const int tid = threadIdx.x;
  const int s0 = blockIdx.x * 64, d0 = blockIdx.y * 64, hz = blockIdx.z;
#pragma unroll
  for (int pp = 0; pp < 2; ++pp) {
    int row = pp * 32 + (tid >> 3), colg = tid & 7;
    u32x4 vv = *(const u32x4*)(V + ((size_t)hz * 2048 + s0 + row) * 128 + d0 + colg * 8);
    *(u32x4*)(&tile[row * 72 + colg * 8]) = vv;
  }
  __syncthreads();
#pragma unroll
  for (int pp = 0; pp < 2; ++pp) {
    int dr = pp * 32 + (tid >> 3), sg = tid & 7;
    u32x4 ov;
#pragma unroll
    for (int e2 = 0; e2 < 4; ++e2)
      ov[e2] = (unsigned)tile[(sg * 8 + 2 * e2) * 72 + dr] |
               ((unsigned)tile[(sg * 8 + 2 * e2 + 1) * 72 + dr] << 16);
    *(u32x4*)(VT + ((size_t)hz * 128 + d0 + dr) * 2048 + s0 + sg * 8) = ov;
  }
}

// ---------------- fused per-head RMSNorm + RoPE (Q and K in one launch) ---------
__global__ __launch_bounds__(256) void rms_rope_all(
    u16* __restrict__ Qb, u16* __restrict__ Kb,
    const float* __restrict__ cosT, const float* __restrict__ sinT,
    const float* __restrict__ qnw, const float* __restrict__ knw) {
  int idx = blockIdx.x * 256 + threadIdx.x;
  int row = idx >> 6;
  int lane = idx & 63;
  u16* rp;
  const float* nw;
  float oscale;
  if (row < 131072) {
    rp = Qb + (size_t)row * 128;
    nw = qnw;
    oscale = 0.08838834764831845f * 1.4426950408889634f;
  } else {
    rp = Kb + (size_t)(row - 131072) * 128;
    nw = knw;
    oscale = 1.0f;
  }
  int s = row & 2047;
  float x0 = b2f(rp[lane]);
  float x1 = b2f(rp[lane + 64]);
  float ss = x0 * x0 + x1 * x1;
#pragma unroll
  for (int m = 32; m >= 1; m >>= 1) ss += __shfl_xor(ss, m);
  float inv = rsqrtf(ss * (1.0f / 128.0f) + 1e-6f);
  x0 *= inv * nw[lane];
  x1 *= inv * nw[lane + 64];
  float c0 = cosT[s * 128 + lane], s0 = sinT[s * 128 + lane];
  float c1 = cosT[s * 128 + lane + 64], s1 = sinT[s * 128 + lane + 64];
  rp[lane] = f2b((x0 * c0 - x1 * s0) * oscale);
  rp[lane + 64] = f2b((x1 * c1 + x0 * s1) * oscale);
}

// ---------------- causal GQA flash attention (2 q-frags/wave + K/V dbuf) --------
// NO-MAX softmax: after RMSNorm+RoPE, |S*log2e| <= 128/sqrt(128)*log2e = 16.4,
// so exp2(S) <= 8.2e4 and row sums <= 1.7e8 -- safely inside fp32/bf16 range.
// P = exp2(S) directly; masked entries -1e30 -> exp2 -> 0. Normalization by
// lrun (ones-MFMA row-sum) cancels the scale. Removes max chain, 4 shfl, and
// defer-rescale state.
__global__ __launch_bounds__(256, 2) void attn_fwd(const u16* __restrict__ Q,
                                                   const u16* __restrict__ Kg,
                                                   const u16* __restrict__ Vg,
                                                   u16* __restrict__ AO) {
  __shared__ __attribute__((aligned(16))) u16 Ks[2][64 * 128];
  __shared__ __attribute__((aligned(16))) u16 Vt[2][128 * 64];
  __shared__ __attribute__((aligned(16))) u16 Plds[4][32 * 64];
  const int tid = threadIdx.x;
  const int lane = tid & 63;
  const int w = tid >> 6;
  const int r = lane & 15, g = lane >> 4;
  const int p = blockIdx.x, h = blockIdx.y, b = blockIdx.z;
  const int hkv = h >> 2;

  const u16* Kp = Kg + (((size_t)b * 8 + hkv) * 2048) * 128;
  const u16* Vp = Vg + (((size_t)b * 8 + hkv) * 128) * 2048;

  const short one_bf = (short)0x3F80;
  const bf16x8 vones = {one_bf, one_bf, one_bf, one_bf, one_bf, one_bf, one_bf, one_bf};

#pragma unroll 1
  for (int phase = 0; phase < 2; ++phase) {
    const int qt = phase == 0 ? (15 - p) : p;
    const u16* Qp = Q + (((size_t)b * 32 + h) * 2048 + qt * 128 + w * 32) * 128;

    bf16x8 qf[2][4];
#pragma unroll
    for (int f = 0; f < 2; ++f)
#pragma unroll
      for (int kk = 0; kk < 4; ++kk)
        qf[f][kk] = *(const bf16x8*)(Qp + (f * 16 + r) * 128 + kk * 32 + g * 8);

    f32x4 off[2][8];
#pragma unroll
    for (int f = 0; f < 2; ++f)
#pragma unroll
      for (int i = 0; i < 8; ++i) off[f][i] = (f32x4){0.f, 0.f, 0.f, 0.f};
    f32x4 lr4[2] = {(f32x4){0.f, 0.f, 0.f, 0.f}, (f32x4){0.f, 0.f, 0.f, 0.f}};
    const int qg0 = qt * 128 + w * 32 + r;
    const int qg1 = qg0 + 16;

    const u16* kst[4];
    const u16* vst[4];
#pragma unroll
    for (int c = 0; c < 4; ++c) {
      int t = c * 256 + tid;
      kst[c] = Kp + (size_t)(t >> 4) * 128 + (size_t)(((t & 15) ^ ((t >> 4) & 7)) * 8);
      int d = t >> 3;
      vst[c] = Vp + (size_t)d * 2048 + (size_t)(((t & 7) ^ ((d >> 1) & 7)) * 8);
    }
    auto stageKV = [&](int buf) {
#pragma unroll
      for (int c = 0; c < 4; ++c) {
        gload16(kst[c], (char*)&Ks[buf][0] + c * 4096 + w * 1024);
        kst[c] += 64 * 128;
      }
#pragma unroll
      for (int c = 0; c < 4; ++c) {
        gload16(vst[c], (char*)&Vt[buf][0] + c * 4096 + w * 1024);
        vst[c] += 64;
      }
    };

    const int nu = 2 * qt + 2;

    stageKV(0);
    WAITV(0);
    BAR();

    for (int kt = 0; kt < nu; ++kt) {
      const int cur = kt & 1;
      if (kt + 1 < nu) stageKV(cur ^ 1);

      const char* KsC = (const char*)&Ks[cur][0];
      const char* VtC = (const char*)&Vt[cur][0];

      // ---- S^T = K Q^T (swapped): D col = q = r, row = kv = ni*16 + g*4 + j
      f32x4 sc0[4], sc1[4];
#pragma unroll
      for (int ni = 0; ni < 4; ++ni) {
        f32x4 a0 = (f32x4){0.f, 0.f, 0.f, 0.f};
        f32x4 a1 = (f32x4){0.f, 0.f, 0.f, 0.f};
        int ro = ni * 16 + r;
#pragma unroll
        for (int kk = 0; kk < 4; ++kk) {
          int slot = (ro * 16 + kk * 4 + g) ^ (ro & 7);
          bf16x8 kf = *(const bf16x8*)(KsC + slot * 16);
          a0 = MFMA(kf, qf[0][kk], a0, 0, 0, 0);
          a1 = MFMA(kf, qf[1][kk], a1, 0, 0, 0);
        }
        sc0[ni] = a0;
        sc1[ni] = a1;
      }

      // ---- mask (diagonal units only: kt >= 2*qt); no max tracking needed
      if (kt >= 2 * qt) {
#pragma unroll
        for (int ni = 0; ni < 4; ++ni)
#pragma unroll
          for (int j = 0; j < 4; ++j) {
            int kvg = kt * 64 + ni * 16 + g * 4 + j;
            sc0[ni][j] = (kvg > qg0) ? -1e30f : sc0[ni][j];
            sc1[ni][j] = (kvg > qg1) ? -1e30f : sc1[ni][j];
          }
      }

      // ---- P = exp2(S) (no max subtraction; bounded by 2^16.4), pack
      {
        char* pw = (char*)&Plds[w][0];
        int sw = (r & 7) << 4;
#pragma unroll
        for (int ni = 0; ni < 4; ++ni) {
          u32x2 pr0, pr1;
          pr0[0] = cvtpk(exp2f(sc0[ni][0]), exp2f(sc0[ni][1]));
          pr0[1] = cvtpk(exp2f(sc0[ni][2]), exp2f(sc0[ni][3]));
          pr1[0] = cvtpk(exp2f(sc1[ni][0]), exp2f(sc1[ni][1]));
          pr1[1] = cvtpk(exp2f(sc1[ni][2]), exp2f(sc1[ni][3]));
          *(u32x2*)(pw + ((r * 128 + ni * 32 + g * 8) ^ sw)) = pr0;
          *(u32x2*)(pw + (((16 + r) * 128 + ni * 32 + g * 8) ^ sw)) = pr1;
        }
      }
      bf16x8 pa[2][2];
      {
        const char* pw = (const char*)&Plds[w][0];
        int sw = (r & 7) << 4;
#pragma unroll
        for (int kk = 0; kk < 2; ++kk) {
          pa[0][kk] = *(const bf16x8*)(pw + ((r * 128 + kk * 64 + g * 16) ^ sw));
          pa[1][kk] = *(const bf16x8*)(pw + (((16 + r) * 128 + kk * 64 + g * 16) ^ sw));
        }
      }

      // ---- row-sums via ones-MFMA
      lr4[0] = MFMA(pa[0][0], vones, lr4[0], 0, 0, 0);
      lr4[0] = MFMA(pa[0][1], vones, lr4[0], 0, 0, 0);
      lr4[1] = MFMA(pa[1][0], vones, lr4[1], 0, 0, 0);
      lr4[1] = MFMA(pa[1][1], vones, lr4[1], 0, 0, 0);

      // ---- O += P V : each vf load feeds BOTH frags
#pragma unroll
      for (int dd = 0; dd < 8; ++dd) {
        int d = dd * 16 + r;
#pragma unroll
        for (int kk = 0; kk < 2; ++kk) {
          int ph = (kk * 4 + g) ^ ((r >> 1) & 7);
          bf16x8 vf = *(const bf16x8*)(VtC + (size_t)d * 128 + ph * 16);
          off[0][dd] = MFMA(pa[0][kk], vf, off[0][dd], 0, 0, 0);
          off[1][dd] = MFMA(pa[1][kk], vf, off[1][dd], 0, 0, 0);
        }
      }

      WAITV(0);
      BAR();
    }

#pragma unroll
    for (int f = 0; f < 2; ++f) {
      f32x4 il4;
#pragma unroll
      for (int j = 0; j < 4; ++j) il4[j] = 1.0f / lr4[f][j];
      const size_t ob = (size_t)b * 2048 + qt * 128 + w * 32 + f * 16 + g * 4;
#pragma unroll
      for (int dd = 0; dd < 8; ++dd) {
        AO[(ob + 0) * 4096 + h * 128 + dd * 16 + r] = f2b(off[f][dd][0] * il4[0]);
        AO[(ob + 1) * 4096 + h * 128 + dd * 16 + r] = f2b(off[f][dd][1] * il4[1]);
        AO[(ob + 2) * 4096 + h * 128 + dd * 16 + r] = f2b(off[f][dd][2] * il4[2]);
        AO[(ob + 3) * 4096 + h * 128 + dd * 16 + r] = f2b(off[f][dd][3] * il4[3]);
      }
    }
  }
}

// ---------------- launch ----------------
extern "C" void kernel_launch(void* const* d_in, const int* in_sizes, int n_in,
                              void* d_out, int out_size, void* d_ws, size_t ws_size,
                              hipStream_t stream) {
  (void)in_sizes; (void)n_in; (void)out_size; (void)ws_size;
  const float* hs = (const float*)d_in[0];
  const float* cosT = (const float*)d_in[1];
  const float* sinT = (const float*)d_in[2];
  const float* wq = (const float*)d_in[3];
  const float* wk = (const float*)d_in[4];
  const float* wv = (const float*)d_in[5];
  const float* wo = (const float*)d_in[6];
  const float* qnw = (const float*)d_in[7];
  const float* knw = (const float*)d_in[8];
  float* out = (float*)d_out;

  char* ws = (char*)d_ws;
  u16* hsb  = (u16*)(ws);                   // [4096,2048]      16 MB
  u16* wqkv = (u16*)(ws + 16777216);        // [6144,2048]      24 MB
  u16* wob  = (u16*)(ws + 41943040);        // [2048,4096]      16 MB
  u16* Qb   = (u16*)(ws + 58720256);        // [2,32,2048,128]  32 MB
  u16* Kb   = (u16*)(ws + 92274688);        // [2,8,2048,128]    8 MB
  u16* VTb  = (u16*)(ws + 100663296);       // [2,8,128,2048]    8 MB (transposed)
  u16* AO   = (u16*)(ws + 109051904);       // [4096,4096]      32 MB
  u16* Vnrm = AO;                           // dead before attn

  // 1) fp32 -> bf16 (all tensors, one launch)
  cvt_all<<<14336, 256, 0, stream>>>(hs, wq, wk, wv, wo, hsb, wqkv, wob);

  // 2) fused QKV projection (256^2 8-phase), V in normal layout
  gemm256<0><<<384, 512, 0, stream>>>(hsb, wqkv, Qb, Kb, Vnrm, nullptr, 2048, 24, 384);

  // 2b) V -> V^T [b,hkv,d,s]
  transpose_v<<<dim3(32, 2, 16), 256, 0, stream>>>(Vnrm, VTb);

  // 3) per-head RMSNorm + RoPE for Q and K (one launch)
  rms_rope_all<<<40960, 256, 0, stream>>>(Qb, Kb, cosT, sinT, qnw, knw);

  // 4) causal GQA flash attention (QBLK=128, paired {15-p,p}) -> AO bf16
  attn_fwd<<<dim3(8, 32, 2), 256, 0, stream>>>(Qb, Kb, VTb, AO);

  // 5) output projection (256^2 8-phase) -> fp32 d_out
  gemm256<1><<<128, 512, 0, stream>>>(AO, wob, nullptr, nullptr, nullptr, out,
                                      4096, 8, 128);
}